// Round 1
// baseline (912.777 us; speedup 1.0000x reference)
//
#include <hip/hip_runtime.h>

#define NTOK 16384
#define DMODEL 1024
#define DHID 4096
#define NEXP 8
#define CAP 512

typedef __attribute__((ext_vector_type(8))) short bfrag_t;
typedef __attribute__((ext_vector_type(4))) float ffrag_t;

__device__ __forceinline__ unsigned short f2bf(float f) {
  unsigned u = __float_as_uint(f);
  u += 0x7FFFu + ((u >> 16) & 1u);
  return (unsigned short)(u >> 16);
}

__device__ __forceinline__ float gelu_tanh(float x) {
  return 0.5f * x * (1.0f + tanhf(0.7978845608028654f * (x + 0.044715f * x * x * x)));
}

// ---------------- convert f32 -> bf16 flat ----------------
__global__ void k_convert_bf16(const float* __restrict__ in, unsigned short* __restrict__ out, int n4) {
  int i = blockIdx.x * blockDim.x + threadIdx.x;
  int stride = gridDim.x * blockDim.x;
  for (; i < n4; i += stride) {
    float4 v = ((const float4*)in)[i];
    ushort4 o;
    o.x = f2bf(v.x); o.y = f2bf(v.y); o.z = f2bf(v.z); o.w = f2bf(v.w);
    ((ushort4*)out)[i] = o;
  }
}

// ------------- transpose+convert: in [K,N] f32 -> out [N,K] bf16, batch z -------------
__global__ void k_trans_conv(const float* __restrict__ in, unsigned short* __restrict__ out, int K, int N) {
  const size_t zb = blockIdx.z;
  in  += zb * (size_t)K * N;
  out += zb * (size_t)N * K;
  __shared__ float tile[32][33];
  const int n0 = blockIdx.x * 32, k0 = blockIdx.y * 32;
  const int tx = threadIdx.x & 31, ty = threadIdx.x >> 5;
#pragma unroll
  for (int i = 0; i < 4; ++i) {
    int k = ty + i * 8;
    tile[k][tx] = in[(size_t)(k0 + k) * N + n0 + tx];
  }
  __syncthreads();
#pragma unroll
  for (int i = 0; i < 4; ++i) {
    int n = ty + i * 8;
    out[(size_t)(n0 + n) * K + k0 + tx] = f2bf(tile[tx][n]);
  }
}

// ---------------- router: probs[e][t] ----------------
__global__ __launch_bounds__(256) void k_router(const float* __restrict__ x, const float* __restrict__ gw,
                                                const float* __restrict__ gb, const float* __restrict__ temp,
                                                float* __restrict__ probs) {
  __shared__ float gws[DMODEL * NEXP];
  for (int i = threadIdx.x; i < DMODEL * NEXP; i += 256) gws[i] = gw[i];
  __syncthreads();
  const int wave = threadIdx.x >> 6, lane = threadIdx.x & 63;
  const int t = blockIdx.x * 4 + wave;
  const float* xr = x + (size_t)t * DMODEL;
  float acc[NEXP];
#pragma unroll
  for (int e = 0; e < NEXP; ++e) acc[e] = 0.f;
  for (int d = lane; d < DMODEL; d += 64) {
    float xv = xr[d];
#pragma unroll
    for (int e = 0; e < NEXP; ++e) acc[e] += xv * gws[d * NEXP + e];
  }
#pragma unroll
  for (int off = 32; off >= 1; off >>= 1) {
#pragma unroll
    for (int e = 0; e < NEXP; ++e) acc[e] += __shfl_xor(acc[e], off);
  }
  if (lane == 0) {
    float st = fmaxf(temp[0], 0.1f);
    float m = -1e30f;
#pragma unroll
    for (int e = 0; e < NEXP; ++e) { acc[e] = (acc[e] + gb[e]) / st; m = fmaxf(m, acc[e]); }
    float s = 0.f;
#pragma unroll
    for (int e = 0; e < NEXP; ++e) { acc[e] = expf(acc[e] - m); s += acc[e]; }
    float inv = 1.f / s;
#pragma unroll
    for (int e = 0; e < NEXP; ++e) probs[(size_t)e * NTOK + t] = acc[e] * inv;
  }
}

// ---------------- exact top-512 per expert (radix select, tie -> lowest index) ----------------
__global__ __launch_bounds__(256) void k_topk(const float* __restrict__ probs, int* __restrict__ tok,
                                              float* __restrict__ scores, int* __restrict__ eqbuf) {
  const int e = blockIdx.x;
  const float* p = probs + (size_t)e * NTOK;
  int* eq = eqbuf + (size_t)e * NTOK;
  __shared__ int hist[256];
  __shared__ unsigned sh_pref;
  __shared__ int sh_k, sh_gt, sh_eq, sh_cnt;
  const int tid = threadIdx.x;
  if (tid == 0) { sh_pref = 0u; sh_k = CAP; }
  __syncthreads();
  for (int pass = 3; pass >= 0; --pass) {
    hist[tid] = 0;
    __syncthreads();
    const unsigned pref = sh_pref;
    const int shift = pass * 8;
    for (int t = tid; t < NTOK; t += 256) {
      unsigned key = __float_as_uint(p[t]);
      bool cand = (pass == 3) || ((key >> (shift + 8)) == pref);
      if (cand) atomicAdd(&hist[(key >> shift) & 255], 1);
    }
    __syncthreads();
    if (tid == 0) {
      int k = sh_k;
      int d = 255;
      while (hist[d] < k) { k -= hist[d]; --d; }
      sh_k = k;
      sh_pref = (pref << 8) | (unsigned)d;
    }
    __syncthreads();
  }
  const unsigned Kstar = sh_pref;
  const int need_eq = sh_k;
  if (tid == 0) { sh_gt = 0; sh_eq = 0; }
  __syncthreads();
  for (int t = tid; t < NTOK; t += 256) {
    unsigned key = __float_as_uint(p[t]);
    if (key > Kstar) {
      int pos = atomicAdd(&sh_gt, 1);
      tok[e * CAP + pos] = t;
      scores[e * CAP + pos] = p[t];
    } else if (key == Kstar) {
      int q = atomicAdd(&sh_eq, 1);
      eq[q] = t;
    }
  }
  __syncthreads();
  const int cg = sh_gt, ce = sh_eq;
  if (ce <= need_eq) {
    for (int j = tid; j < ce; j += 256) {
      tok[e * CAP + cg + j] = eq[j];
      scores[e * CAP + cg + j] = p[eq[j]];
    }
  } else {
    int lo = 0, hi = NTOK - 1;
    while (lo < hi) {
      int mid = (lo + hi) >> 1;
      if (tid == 0) sh_cnt = 0;
      __syncthreads();
      for (int j = tid; j < ce; j += 256)
        if (eq[j] <= mid) atomicAdd(&sh_cnt, 1);
      __syncthreads();
      if (sh_cnt >= need_eq) hi = mid; else lo = mid + 1;
      __syncthreads();
    }
    if (tid == 0) sh_cnt = 0;
    __syncthreads();
    for (int j = tid; j < ce; j += 256) {
      if (eq[j] <= lo) {
        int pos = cg + atomicAdd(&sh_cnt, 1);
        tok[e * CAP + pos] = eq[j];
        scores[e * CAP + pos] = p[eq[j]];
      }
    }
  }
}

// ---------------- gather selected tokens (bf16 rows) ----------------
__global__ void k_gather(const unsigned short* __restrict__ xb, const int* __restrict__ tok,
                         unsigned short* __restrict__ atok) {
  const int row = blockIdx.x;
  const int t = tok[row];
  const uint2* src = (const uint2*)(xb + (size_t)t * DMODEL);
  uint2* dst = (uint2*)(atok + (size_t)row * DMODEL);
  dst[threadIdx.x] = src[threadIdx.x];
}

// ---------------- NT GEMM: C[M,N] = act(A[M,K] @ Bt[N,K]^T + bias) ----------------
// MODE 0: outB = bf16(gelu(v))   (batched: out row = zb*M + m)
// MODE 1: outF[m*N+n] = v        (plain overwrite, zb==0)
// MODE 2: atomicAdd(outF[tok[zb*M+m]*N + n], v * scale[zb*M+m])
template <int MODE>
__global__ __launch_bounds__(256) void k_gemm_nt(
    const unsigned short* __restrict__ A, const unsigned short* __restrict__ Bt,
    const float* __restrict__ bias, float* __restrict__ outF, unsigned short* __restrict__ outB,
    const int* __restrict__ tok, const float* __restrict__ scale, int M, int N, int K) {
  const int zb = blockIdx.z;
  A += (size_t)zb * M * K;
  Bt += (size_t)zb * N * K;
  const float* bz = bias + (size_t)zb * N;

  const int m0 = blockIdx.x * 128, n0 = blockIdx.y * 128;
  const int tid = threadIdx.x, wave = tid >> 6, lane = tid & 63;
  const int wm = (wave >> 1) * 64, wn = (wave & 1) * 64;

  __shared__ unsigned short As[128 * 64];
  __shared__ unsigned short Bs[128 * 64];

  ffrag_t acc[4][4];
#pragma unroll
  for (int i = 0; i < 4; ++i)
#pragma unroll
    for (int j = 0; j < 4; ++j)
#pragma unroll
      for (int r = 0; r < 4; ++r) acc[i][j][r] = 0.f;

  // staging geometry: LDS linear dest (granule L -> bytes L*16), source pre-swizzled:
  // LDS slot (r, gs) holds logical granule g = gs ^ (r&7)
  int rr[4], gg[4], lb[4];
#pragma unroll
  for (int it = 0; it < 4; ++it) {
    int L = it * 256 + wave * 64 + lane;
    rr[it] = L >> 3;
    gg[it] = (L & 7) ^ (rr[it] & 7);
    lb[it] = (it * 256 + wave * 64) * 16;  // wave-uniform byte base; HW adds lane*16
  }

  for (int kt = 0; kt < K; kt += 64) {
#pragma unroll
    for (int it = 0; it < 4; ++it) {
      const unsigned short* sA = A + (size_t)(m0 + rr[it]) * K + kt + gg[it] * 8;
      const unsigned short* sB = Bt + (size_t)(n0 + rr[it]) * K + kt + gg[it] * 8;
      __builtin_amdgcn_global_load_lds((const __attribute__((address_space(1))) unsigned int*)sA,
                                       (__attribute__((address_space(3))) unsigned int*)((char*)As + lb[it]),
                                       16, 0, 0);
      __builtin_amdgcn_global_load_lds((const __attribute__((address_space(1))) unsigned int*)sB,
                                       (__attribute__((address_space(3))) unsigned int*)((char*)Bs + lb[it]),
                                       16, 0, 0);
    }
    __syncthreads();
#pragma unroll
    for (int kk = 0; kk < 2; ++kk) {
      bfrag_t af[4], bf[4];
      const int gl = kk * 4 + (lane >> 4);
#pragma unroll
      for (int mi = 0; mi < 4; ++mi) {
        int r = wm + mi * 16 + (lane & 15);
        af[mi] = *(const bfrag_t*)&As[r * 64 + ((gl ^ (r & 7)) * 8)];
      }
#pragma unroll
      for (int ni = 0; ni < 4; ++ni) {
        int r = wn + ni * 16 + (lane & 15);
        bf[ni] = *(const bfrag_t*)&Bs[r * 64 + ((gl ^ (r & 7)) * 8)];
      }
#pragma unroll
      for (int mi = 0; mi < 4; ++mi)
#pragma unroll
        for (int ni = 0; ni < 4; ++ni)
          acc[mi][ni] = __builtin_amdgcn_mfma_f32_16x16x32_bf16(af[mi], bf[ni], acc[mi][ni], 0, 0, 0);
    }
    __syncthreads();
  }

  // epilogue: C/D layout col = lane&15, row = (lane>>4)*4 + reg
  const int rsub = (lane >> 4) * 4, csub = lane & 15;
#pragma unroll
  for (int ni = 0; ni < 4; ++ni) {
    const int n = n0 + wn + ni * 16 + csub;
    const float bv = bz[n];
#pragma unroll
    for (int mi = 0; mi < 4; ++mi) {
#pragma unroll
      for (int r = 0; r < 4; ++r) {
        const int m = m0 + wm + mi * 16 + rsub + r;
        float v = acc[mi][ni][r] + bv;
        if (MODE == 0) {
          outB[((size_t)zb * M + m) * N + n] = f2bf(gelu_tanh(v));
        } else if (MODE == 1) {
          outF[(size_t)m * N + n] = v;
        } else {
          const int t = tok[zb * M + m];
          const float s = scale[zb * M + m];
          atomicAdd(&outF[(size_t)t * N + n], v * s);
        }
      }
    }
  }
}

extern "C" void kernel_launch(void* const* d_in, const int* in_sizes, int n_in,
                              void* d_out, int out_size, void* d_ws, size_t ws_size,
                              hipStream_t stream) {
  const float* x      = (const float*)d_in[0];
  const float* gate_w = (const float*)d_in[1];
  const float* gate_b = (const float*)d_in[2];
  const float* temp   = (const float*)d_in[3];
  const float* sw1    = (const float*)d_in[4];
  const float* sb1    = (const float*)d_in[5];
  const float* sw2    = (const float*)d_in[6];
  const float* sb2    = (const float*)d_in[7];
  const float* ew1    = (const float*)d_in[8];
  const float* eb1    = (const float*)d_in[9];
  const float* ew2    = (const float*)d_in[10];
  const float* eb2    = (const float*)d_in[11];
  float* out = (float*)d_out;

  char* ws = (char*)d_ws;
  size_t o = 0;
  auto take = [&](size_t bytes) { char* p = ws + o; o += (bytes + 255) & ~(size_t)255; return p; };
  unsigned short* x_bf = (unsigned short*)take((size_t)NTOK * DMODEL * 2);
  unsigned short* w1t  = (unsigned short*)take((size_t)DMODEL * DHID * 2);
  unsigned short* w2t  = (unsigned short*)take((size_t)DHID * DMODEL * 2);
  unsigned short* ew1t = (unsigned short*)take((size_t)NEXP * DMODEL * DHID * 2);
  unsigned short* ew2t = (unsigned short*)take((size_t)NEXP * DHID * DMODEL * 2);
  float* probs         = (float*)take((size_t)NEXP * NTOK * 4);
  int* tok             = (int*)take((size_t)NEXP * CAP * 4);
  float* scores        = (float*)take((size_t)NEXP * CAP * 4);
  int* eqbuf           = (int*)take((size_t)NEXP * NTOK * 4);
  unsigned short* atok = (unsigned short*)take((size_t)NEXP * CAP * DMODEL * 2);
  unsigned short* he   = (unsigned short*)take((size_t)NEXP * CAP * DHID * 2);
  unsigned short* hs   = (unsigned short*)take((size_t)NTOK * DHID * 2);

  // prep: bf16 conversions + weight transposes
  k_convert_bf16<<<4096, 256, 0, stream>>>(x, x_bf, NTOK * DMODEL / 4);
  k_trans_conv<<<dim3(DHID / 32, DMODEL / 32, 1), 256, 0, stream>>>(sw1, w1t, DMODEL, DHID);
  k_trans_conv<<<dim3(DMODEL / 32, DHID / 32, 1), 256, 0, stream>>>(sw2, w2t, DHID, DMODEL);
  k_trans_conv<<<dim3(DHID / 32, DMODEL / 32, NEXP), 256, 0, stream>>>(ew1, ew1t, DMODEL, DHID);
  k_trans_conv<<<dim3(DMODEL / 32, DHID / 32, NEXP), 256, 0, stream>>>(ew2, ew2t, DHID, DMODEL);

  // router + top-k + gather
  k_router<<<NTOK / 4, 256, 0, stream>>>(x, gate_w, gate_b, temp, probs);
  k_topk<<<NEXP, 256, 0, stream>>>(probs, tok, scores, eqbuf);
  k_gather<<<NEXP * CAP, 256, 0, stream>>>(x_bf, tok, atok);

  // shared FFN
  k_gemm_nt<0><<<dim3(NTOK / 128, DHID / 128, 1), 256, 0, stream>>>(
      x_bf, w1t, sb1, nullptr, hs, nullptr, nullptr, NTOK, DHID, DMODEL);
  k_gemm_nt<1><<<dim3(NTOK / 128, DMODEL / 128, 1), 256, 0, stream>>>(
      hs, w2t, sb2, out, nullptr, nullptr, nullptr, NTOK, DMODEL, DHID);

  // routed experts (batched over z = expert)
  k_gemm_nt<0><<<dim3(CAP / 128, DHID / 128, NEXP), 256, 0, stream>>>(
      atok, ew1t, eb1, nullptr, he, nullptr, nullptr, CAP, DHID, DMODEL);
  k_gemm_nt<2><<<dim3(CAP / 128, DMODEL / 128, NEXP), 256, 0, stream>>>(
      he, ew2t, eb2, out, nullptr, tok, scores, CAP, DMODEL, DHID);
}

// Round 2
// 804.972 us; speedup vs baseline: 1.1339x; 1.1339x over previous
//
#include <hip/hip_runtime.h>

#define NTOK 16384
#define DMODEL 1024
#define DHID 4096
#define NEXP 8
#define CAP 512

typedef __attribute__((ext_vector_type(8))) short bfrag_t;
typedef __attribute__((ext_vector_type(4))) float ffrag_t;

__device__ __forceinline__ unsigned short f2bf(float f) {
  unsigned u = __float_as_uint(f);
  u += 0x7FFFu + ((u >> 16) & 1u);
  return (unsigned short)(u >> 16);
}

__device__ __forceinline__ float gelu_tanh(float x) {
  return 0.5f * x * (1.0f + tanhf(0.7978845608028654f * (x + 0.044715f * x * x * x)));
}

// ---------------- convert f32 -> bf16 flat ----------------
__global__ void k_convert_bf16(const float* __restrict__ in, unsigned short* __restrict__ out, int n4) {
  int i = blockIdx.x * blockDim.x + threadIdx.x;
  int stride = gridDim.x * blockDim.x;
  for (; i < n4; i += stride) {
    float4 v = ((const float4*)in)[i];
    ushort4 o;
    o.x = f2bf(v.x); o.y = f2bf(v.y); o.z = f2bf(v.z); o.w = f2bf(v.w);
    ((ushort4*)out)[i] = o;
  }
}

// ------------- transpose+convert: in [K,N] f32 -> out [N,K] bf16, batch z -------------
__global__ void k_trans_conv(const float* __restrict__ in, unsigned short* __restrict__ out, int K, int N) {
  const size_t zb = blockIdx.z;
  in  += zb * (size_t)K * N;
  out += zb * (size_t)N * K;
  __shared__ float tile[32][33];
  const int n0 = blockIdx.x * 32, k0 = blockIdx.y * 32;
  const int tx = threadIdx.x & 31, ty = threadIdx.x >> 5;
#pragma unroll
  for (int i = 0; i < 4; ++i) {
    int k = ty + i * 8;
    tile[k][tx] = in[(size_t)(k0 + k) * N + n0 + tx];
  }
  __syncthreads();
#pragma unroll
  for (int i = 0; i < 4; ++i) {
    int n = ty + i * 8;
    out[(size_t)(n0 + n) * K + k0 + tx] = f2bf(tile[tx][n]);
  }
}

// ---------------- router: probs[e][t] ----------------
__global__ __launch_bounds__(256) void k_router(const float* __restrict__ x, const float* __restrict__ gw,
                                                const float* __restrict__ gb, const float* __restrict__ temp,
                                                float* __restrict__ probs) {
  __shared__ float gws[DMODEL * NEXP];
  for (int i = threadIdx.x; i < DMODEL * NEXP; i += 256) gws[i] = gw[i];
  __syncthreads();
  const int wave = threadIdx.x >> 6, lane = threadIdx.x & 63;
  const int t = blockIdx.x * 4 + wave;
  const float* xr = x + (size_t)t * DMODEL;
  float acc[NEXP];
#pragma unroll
  for (int e = 0; e < NEXP; ++e) acc[e] = 0.f;
  for (int d = lane; d < DMODEL; d += 64) {
    float xv = xr[d];
#pragma unroll
    for (int e = 0; e < NEXP; ++e) acc[e] += xv * gws[d * NEXP + e];
  }
#pragma unroll
  for (int off = 32; off >= 1; off >>= 1) {
#pragma unroll
    for (int e = 0; e < NEXP; ++e) acc[e] += __shfl_xor(acc[e], off);
  }
  if (lane == 0) {
    float st = fmaxf(temp[0], 0.1f);
    float m = -1e30f;
#pragma unroll
    for (int e = 0; e < NEXP; ++e) { acc[e] = (acc[e] + gb[e]) / st; m = fmaxf(m, acc[e]); }
    float s = 0.f;
#pragma unroll
    for (int e = 0; e < NEXP; ++e) { acc[e] = expf(acc[e] - m); s += acc[e]; }
    float inv = 1.f / s;
#pragma unroll
    for (int e = 0; e < NEXP; ++e) probs[(size_t)e * NTOK + t] = acc[e] * inv;
  }
}

// ---------------- exact top-512 per expert (radix select, tie -> lowest index) ----------------
__global__ __launch_bounds__(256) void k_topk(const float* __restrict__ probs, int* __restrict__ tok,
                                              float* __restrict__ scores, int* __restrict__ eqbuf) {
  const int e = blockIdx.x;
  const float* p = probs + (size_t)e * NTOK;
  int* eq = eqbuf + (size_t)e * NTOK;
  __shared__ int hist[256];
  __shared__ unsigned sh_pref;
  __shared__ int sh_k, sh_gt, sh_eq, sh_cnt;
  const int tid = threadIdx.x;
  if (tid == 0) { sh_pref = 0u; sh_k = CAP; }
  __syncthreads();
  for (int pass = 3; pass >= 0; --pass) {
    hist[tid] = 0;
    __syncthreads();
    const unsigned pref = sh_pref;
    const int shift = pass * 8;
    for (int t = tid; t < NTOK; t += 256) {
      unsigned key = __float_as_uint(p[t]);
      bool cand = (pass == 3) || ((key >> (shift + 8)) == pref);
      if (cand) atomicAdd(&hist[(key >> shift) & 255], 1);
    }
    __syncthreads();
    if (tid == 0) {
      int k = sh_k;
      int d = 255;
      while (hist[d] < k) { k -= hist[d]; --d; }
      sh_k = k;
      sh_pref = (pref << 8) | (unsigned)d;
    }
    __syncthreads();
  }
  const unsigned Kstar = sh_pref;
  const int need_eq = sh_k;
  if (tid == 0) { sh_gt = 0; sh_eq = 0; }
  __syncthreads();
  for (int t = tid; t < NTOK; t += 256) {
    unsigned key = __float_as_uint(p[t]);
    if (key > Kstar) {
      int pos = atomicAdd(&sh_gt, 1);
      tok[e * CAP + pos] = t;
      scores[e * CAP + pos] = p[t];
    } else if (key == Kstar) {
      int q = atomicAdd(&sh_eq, 1);
      eq[q] = t;
    }
  }
  __syncthreads();
  const int cg = sh_gt, ce = sh_eq;
  if (ce <= need_eq) {
    for (int j = tid; j < ce; j += 256) {
      tok[e * CAP + cg + j] = eq[j];
      scores[e * CAP + cg + j] = p[eq[j]];
    }
  } else {
    int lo = 0, hi = NTOK - 1;
    while (lo < hi) {
      int mid = (lo + hi) >> 1;
      if (tid == 0) sh_cnt = 0;
      __syncthreads();
      for (int j = tid; j < ce; j += 256)
        if (eq[j] <= mid) atomicAdd(&sh_cnt, 1);
      __syncthreads();
      if (sh_cnt >= need_eq) hi = mid; else lo = mid + 1;
      __syncthreads();
    }
    if (tid == 0) sh_cnt = 0;
    __syncthreads();
    for (int j = tid; j < ce; j += 256) {
      if (eq[j] <= lo) {
        int pos = cg + atomicAdd(&sh_cnt, 1);
        tok[e * CAP + pos] = eq[j];
        scores[e * CAP + pos] = p[eq[j]];
      }
    }
  }
}

// ---------------- gather selected tokens (bf16 rows) ----------------
__global__ void k_gather(const unsigned short* __restrict__ xb, const int* __restrict__ tok,
                         unsigned short* __restrict__ atok) {
  const int row = blockIdx.x;
  const int t = tok[row];
  const uint2* src = (const uint2*)(xb + (size_t)t * DMODEL);
  uint2* dst = (uint2*)(atok + (size_t)row * DMODEL);
  dst[threadIdx.x] = src[threadIdx.x];
}

// =====================================================================================
// 256x256 tile, BK=32, 8 waves (2M x 4N), quad-buffered LDS ring (4 x 32 KB = 128 KB),
// counted-vmcnt pipeline (stage t+3 while computing t; s_waitcnt vmcnt(8) per K-step).
// MODE 0: outB[(zb*M+m)*N+n] = bf16(gelu(v));  MODE 1: outF[m*N+n] = v.
// =====================================================================================
#define WAITV8() asm volatile("s_waitcnt vmcnt(8)" ::: "memory")
#define WAITV4() asm volatile("s_waitcnt vmcnt(4)" ::: "memory")
#define WAITV0() asm volatile("s_waitcnt vmcnt(0)" ::: "memory")

template <int MODE>
__global__ __launch_bounds__(512, 2) void k_gemm_big(
    const unsigned short* __restrict__ A, const unsigned short* __restrict__ Bt,
    const float* __restrict__ bias, float* __restrict__ outF, unsigned short* __restrict__ outB,
    int M, int N, int K) {
  const int zb = blockIdx.z;
  A += (size_t)zb * M * K;
  Bt += (size_t)zb * N * K;
  const float* bz = bias + (size_t)zb * N;

  // T1: bijective XCD-aware swizzle (nwg % 8 == 0 for all our grids)
  const int gx = gridDim.x, nwg = gx * gridDim.y;
  const int id = blockIdx.x + blockIdx.y * gx;
  const int q = nwg >> 3;
  const int sw = (id & 7) * q + (id >> 3);
  const int bx = sw % gx, by = sw / gx;
  const int m0 = bx * 256, n0 = by * 256;

  const int tid = threadIdx.x, wave = tid >> 6, lane = tid & 63;
  const int wm = (wave >> 2) * 128, wn = (wave & 3) * 64;

  __shared__ alignas(16) char lds[4 * 32768];  // ring of 4 K-tiles: [A 16K | B 16K] each

  ffrag_t acc[8][4];
#pragma unroll
  for (int i = 0; i < 8; ++i)
#pragma unroll
    for (int j = 0; j < 4; ++j)
#pragma unroll
      for (int r = 0; r < 4; ++r) acc[i][j][r] = 0.f;

  // staging: LDS linear granule L = it*512 + tid; slot (row=L>>2, gs=L&3) holds
  // logical granule g = gs ^ ((row>>1)&3)  (T2 swizzle, source-side pre-swizzled)
  const unsigned short* sA[2];
  const unsigned short* sB[2];
  int dstOff[2];
#pragma unroll
  for (int it = 0; it < 2; ++it) {
    const int L = it * 512 + tid;
    const int row = L >> 2;
    const int g = (L & 3) ^ ((row >> 1) & 3);
    sA[it] = A + (size_t)(m0 + row) * K + g * 8;
    sB[it] = Bt + (size_t)(n0 + row) * K + g * 8;
    dstOff[it] = (it * 512 + wave * 64) * 16;  // wave-uniform; HW adds lane*16
  }

  // ds_read byte offsets (swizzled on the read side with the same involution)
  int offA[8], offB[4];
#pragma unroll
  for (int mi = 0; mi < 8; ++mi) {
    const int row = wm + mi * 16 + (lane & 15);
    const int gs = (lane >> 4) ^ ((row >> 1) & 3);
    offA[mi] = row * 64 + gs * 16;
  }
#pragma unroll
  for (int ni = 0; ni < 4; ++ni) {
    const int row = wn + ni * 16 + (lane & 15);
    const int gs = (lane >> 4) ^ ((row >> 1) & 3);
    offB[ni] = 16384 + row * 64 + gs * 16;
  }

  const int NT = K >> 5;  // K-tiles of 32

#define STAGE(t)                                                                                   \
  do {                                                                                             \
    const int _b = (t) & 3;                                                                        \
    _Pragma("unroll") for (int it = 0; it < 2; ++it) {                                             \
      __builtin_amdgcn_global_load_lds(                                                            \
          (const __attribute__((address_space(1))) unsigned int*)(sA[it] + (size_t)(t) * 32),      \
          (__attribute__((address_space(3))) unsigned int*)(lds + _b * 32768 + dstOff[it]),        \
          16, 0, 0);                                                                               \
      __builtin_amdgcn_global_load_lds(                                                            \
          (const __attribute__((address_space(1))) unsigned int*)(sB[it] + (size_t)(t) * 32),      \
          (__attribute__((address_space(3))) unsigned int*)(lds + _b * 32768 + 16384 + dstOff[it]),\
          16, 0, 0);                                                                               \
    }                                                                                              \
  } while (0)

  // prologue: 3 tiles in flight (12 loads/thread); wait tile0 (oldest 4) -> vmcnt(8)
  STAGE(0);
  STAGE(1);
  STAGE(2);
  WAITV8();
  __builtin_amdgcn_s_barrier();

  for (int t = 0; t < NT; ++t) {
    if (t + 3 < NT) STAGE(t + 3);

    const char* base = lds + (t & 3) * 32768;
    bfrag_t af[8], bf[4];
#pragma unroll
    for (int mi = 0; mi < 8; ++mi) af[mi] = *(const bfrag_t*)(base + offA[mi]);
#pragma unroll
    for (int ni = 0; ni < 4; ++ni) bf[ni] = *(const bfrag_t*)(base + offB[ni]);

    __builtin_amdgcn_s_setprio(1);
#pragma unroll
    for (int mi = 0; mi < 8; ++mi)
#pragma unroll
      for (int ni = 0; ni < 4; ++ni)
        acc[mi][ni] = __builtin_amdgcn_mfma_f32_16x16x32_bf16(af[mi], bf[ni], acc[mi][ni], 0, 0, 0);
    __builtin_amdgcn_s_setprio(0);

    // counted vmcnt: guarantee tile t+1 landed; never drain to 0 mid-loop
    if (t < NT - 3) {
      WAITV8();
    } else if (t == NT - 3) {
      WAITV4();
    } else if (t == NT - 2) {
      WAITV0();
    }
    if (t != NT - 1) __builtin_amdgcn_s_barrier();
  }

  // epilogue: C/D layout col = lane&15, row = (lane>>4)*4 + reg
  const int rsub = (lane >> 4) * 4, csub = lane & 15;
#pragma unroll
  for (int ni = 0; ni < 4; ++ni) {
    const int n = n0 + wn + ni * 16 + csub;
    const float bv = bz[n];
#pragma unroll
    for (int mi = 0; mi < 8; ++mi) {
#pragma unroll
      for (int r = 0; r < 4; ++r) {
        const int m = m0 + wm + mi * 16 + rsub + r;
        float v = acc[mi][ni][r] + bv;
        if (MODE == 0) {
          outB[((size_t)zb * M + m) * N + n] = f2bf(gelu_tanh(v));
        } else {
          outF[(size_t)m * N + n] = v;
        }
      }
    }
  }
#undef STAGE
}

// ---------------- 128x128 kernel kept for the expert-2 scatter GEMM (256-block shape) --------
__global__ __launch_bounds__(256) void k_gemm_scatter(
    const unsigned short* __restrict__ A, const unsigned short* __restrict__ Bt,
    const float* __restrict__ bias, float* __restrict__ outF,
    const int* __restrict__ tok, const float* __restrict__ scale, int M, int N, int K) {
  const int zb = blockIdx.z;
  A += (size_t)zb * M * K;
  Bt += (size_t)zb * N * K;
  const float* bz = bias + (size_t)zb * N;

  const int m0 = blockIdx.x * 128, n0 = blockIdx.y * 128;
  const int tid = threadIdx.x, wave = tid >> 6, lane = tid & 63;
  const int wm = (wave >> 1) * 64, wn = (wave & 1) * 64;

  __shared__ unsigned short As[128 * 64];
  __shared__ unsigned short Bs[128 * 64];

  ffrag_t acc[4][4];
#pragma unroll
  for (int i = 0; i < 4; ++i)
#pragma unroll
    for (int j = 0; j < 4; ++j)
#pragma unroll
      for (int r = 0; r < 4; ++r) acc[i][j][r] = 0.f;

  int rr[4], gg[4], lb[4];
#pragma unroll
  for (int it = 0; it < 4; ++it) {
    int L = it * 256 + wave * 64 + lane;
    rr[it] = L >> 3;
    gg[it] = (L & 7) ^ (rr[it] & 7);
    lb[it] = (it * 256 + wave * 64) * 16;
  }

  for (int kt = 0; kt < K; kt += 64) {
#pragma unroll
    for (int it = 0; it < 4; ++it) {
      const unsigned short* sA = A + (size_t)(m0 + rr[it]) * K + kt + gg[it] * 8;
      const unsigned short* sB = Bt + (size_t)(n0 + rr[it]) * K + kt + gg[it] * 8;
      __builtin_amdgcn_global_load_lds((const __attribute__((address_space(1))) unsigned int*)sA,
                                       (__attribute__((address_space(3))) unsigned int*)((char*)As + lb[it]),
                                       16, 0, 0);
      __builtin_amdgcn_global_load_lds((const __attribute__((address_space(1))) unsigned int*)sB,
                                       (__attribute__((address_space(3))) unsigned int*)((char*)Bs + lb[it]),
                                       16, 0, 0);
    }
    __syncthreads();
#pragma unroll
    for (int kk = 0; kk < 2; ++kk) {
      bfrag_t af[4], bf[4];
      const int gl = kk * 4 + (lane >> 4);
#pragma unroll
      for (int mi = 0; mi < 4; ++mi) {
        int r = wm + mi * 16 + (lane & 15);
        af[mi] = *(const bfrag_t*)&As[r * 64 + ((gl ^ (r & 7)) * 8)];
      }
#pragma unroll
      for (int ni = 0; ni < 4; ++ni) {
        int r = wn + ni * 16 + (lane & 15);
        bf[ni] = *(const bfrag_t*)&Bs[r * 64 + ((gl ^ (r & 7)) * 8)];
      }
#pragma unroll
      for (int mi = 0; mi < 4; ++mi)
#pragma unroll
        for (int ni = 0; ni < 4; ++ni)
          acc[mi][ni] = __builtin_amdgcn_mfma_f32_16x16x32_bf16(af[mi], bf[ni], acc[mi][ni], 0, 0, 0);
    }
    __syncthreads();
  }

  const int rsub = (lane >> 4) * 4, csub = lane & 15;
#pragma unroll
  for (int ni = 0; ni < 4; ++ni) {
    const int n = n0 + wn + ni * 16 + csub;
    const float bv = bz[n];
#pragma unroll
    for (int mi = 0; mi < 4; ++mi) {
#pragma unroll
      for (int r = 0; r < 4; ++r) {
        const int m = m0 + wm + mi * 16 + rsub + r;
        float v = acc[mi][ni][r] + bv;
        const int t = tok[zb * M + m];
        const float s = scale[zb * M + m];
        atomicAdd(&outF[(size_t)t * N + n], v * s);
      }
    }
  }
}

extern "C" void kernel_launch(void* const* d_in, const int* in_sizes, int n_in,
                              void* d_out, int out_size, void* d_ws, size_t ws_size,
                              hipStream_t stream) {
  const float* x      = (const float*)d_in[0];
  const float* gate_w = (const float*)d_in[1];
  const float* gate_b = (const float*)d_in[2];
  const float* temp   = (const float*)d_in[3];
  const float* sw1    = (const float*)d_in[4];
  const float* sb1    = (const float*)d_in[5];
  const float* sw2    = (const float*)d_in[6];
  const float* sb2    = (const float*)d_in[7];
  const float* ew1    = (const float*)d_in[8];
  const float* eb1    = (const float*)d_in[9];
  const float* ew2    = (const float*)d_in[10];
  const float* eb2    = (const float*)d_in[11];
  float* out = (float*)d_out;

  char* ws = (char*)d_ws;
  size_t o = 0;
  auto take = [&](size_t bytes) { char* p = ws + o; o += (bytes + 255) & ~(size_t)255; return p; };
  unsigned short* x_bf = (unsigned short*)take((size_t)NTOK * DMODEL * 2);
  unsigned short* w1t  = (unsigned short*)take((size_t)DMODEL * DHID * 2);
  unsigned short* w2t  = (unsigned short*)take((size_t)DHID * DMODEL * 2);
  unsigned short* ew1t = (unsigned short*)take((size_t)NEXP * DMODEL * DHID * 2);
  unsigned short* ew2t = (unsigned short*)take((size_t)NEXP * DHID * DMODEL * 2);
  float* probs         = (float*)take((size_t)NEXP * NTOK * 4);
  int* tok             = (int*)take((size_t)NEXP * CAP * 4);
  float* scores        = (float*)take((size_t)NEXP * CAP * 4);
  int* eqbuf           = (int*)take((size_t)NEXP * NTOK * 4);
  unsigned short* atok = (unsigned short*)take((size_t)NEXP * CAP * DMODEL * 2);
  unsigned short* he   = (unsigned short*)take((size_t)NEXP * CAP * DHID * 2);
  unsigned short* hs   = (unsigned short*)take((size_t)NTOK * DHID * 2);

  // prep: bf16 conversions + weight transposes
  k_convert_bf16<<<4096, 256, 0, stream>>>(x, x_bf, NTOK * DMODEL / 4);
  k_trans_conv<<<dim3(DHID / 32, DMODEL / 32, 1), 256, 0, stream>>>(sw1, w1t, DMODEL, DHID);
  k_trans_conv<<<dim3(DMODEL / 32, DHID / 32, 1), 256, 0, stream>>>(sw2, w2t, DHID, DMODEL);
  k_trans_conv<<<dim3(DHID / 32, DMODEL / 32, NEXP), 256, 0, stream>>>(ew1, ew1t, DMODEL, DHID);
  k_trans_conv<<<dim3(DMODEL / 32, DHID / 32, NEXP), 256, 0, stream>>>(ew2, ew2t, DHID, DMODEL);

  // router + top-k + gather
  k_router<<<NTOK / 4, 256, 0, stream>>>(x, gate_w, gate_b, temp, probs);
  k_topk<<<NEXP, 256, 0, stream>>>(probs, tok, scores, eqbuf);
  k_gather<<<NEXP * CAP, 256, 0, stream>>>(x_bf, tok, atok);

  // shared FFN (256^2 pipelined kernel)
  k_gemm_big<0><<<dim3(NTOK / 256, DHID / 256, 1), 512, 0, stream>>>(
      x_bf, w1t, sb1, nullptr, hs, NTOK, DHID, DMODEL);
  k_gemm_big<1><<<dim3(NTOK / 256, DMODEL / 256, 1), 512, 0, stream>>>(
      hs, w2t, sb2, out, nullptr, NTOK, DMODEL, DHID);

  // routed experts: FFN-1 on the big kernel; FFN-2 scatter stays on 128^2 (256 blocks)
  k_gemm_big<0><<<dim3(CAP / 256, DHID / 256, NEXP), 512, 0, stream>>>(
      atok, ew1t, eb1, nullptr, he, CAP, DHID, DMODEL);
  k_gemm_scatter<<<dim3(CAP / 128, DMODEL / 128, NEXP), 256, 0, stream>>>(
      he, ew2t, eb2, out, tok, scores, CAP, DMODEL, DHID);
}